// Round 1
// baseline (16621.574 us; speedup 1.0000x reference)
//
#include <hip/hip_runtime.h>
#include <math.h>

#define BATCH 256
#define SEQ   1024
#define DI    128
#define DH    128
#define DM    144
#define ROWS  2

#define LDS4(p) (*(const float4*)(p))

// Accumulate 8 consecutive elements of a dot product for 2 batch rows sharing
// the same weight column j. c0/c1 point at 8 consecutive LDS floats (aligned 16).
// w points at weight row block (rows i..i+7), leading dim ld.
__device__ __forceinline__ void dot8x2(const float* __restrict__ c0,
                                       const float* __restrict__ c1,
                                       const float* __restrict__ w, int ld, int j,
                                       float& aA0, float& aB0, float& aA1, float& aB1)
{
    const float4 cx0 = LDS4(c0);
    const float4 cy0 = LDS4(c0 + 4);
    const float4 cx1 = LDS4(c1);
    const float4 cy1 = LDS4(c1 + 4);
    const float w0 = w[0*ld + j], w1 = w[1*ld + j], w2 = w[2*ld + j], w3 = w[3*ld + j];
    const float w4 = w[4*ld + j], w5 = w[5*ld + j], w6 = w[6*ld + j], w7 = w[7*ld + j];
    aA0 += cx0.x*w0 + cx0.y*w1 + cx0.z*w2 + cx0.w*w3;
    aB0 += cy0.x*w4 + cy0.y*w5 + cy0.z*w6 + cy0.w*w7;
    aA1 += cx1.x*w0 + cx1.y*w1 + cx1.z*w2 + cx1.w*w3;
    aB1 += cy1.x*w4 + cy1.y*w5 + cy1.z*w6 + cy1.w*w7;
}

__global__ __launch_bounds__(256, 1) void hgru_kernel(
    const float* __restrict__ inputs,
    const float* __restrict__ r_w, const float* __restrict__ r_b,
    const float* __restrict__ z_w, const float* __restrict__ z_b,
    const float* __restrict__ h_w0, const float* __restrict__ h_b0,
    const float* __restrict__ h_w1, const float* __restrict__ h_b1,
    const float* __restrict__ h_w2, const float* __restrict__ h_b2,
    float* __restrict__ out, float* __restrict__ hid_out)
{
    __shared__ __align__(16) float s_x[ROWS][DI];
    __shared__ __align__(16) float s_h[ROWS][DH];
    __shared__ __align__(16) float s_rh[ROWS][DH];
    __shared__ __align__(16) float s_z[ROWS][DH];
    __shared__ __align__(16) float s_y0[ROWS][DM];
    __shared__ __align__(16) float s_y1[ROWS][DM];

    const int tid = threadIdx.x;
    const int b0 = blockIdx.x * ROWS;

    if (tid < DH) { s_h[0][tid] = 0.f; s_h[1][tid] = 0.f; }
    __syncthreads();

    for (int t = 0; t < SEQ; ++t) {
        // ---- load x for both rows
        if (tid < DI) {
            s_x[0][tid] = inputs[((size_t)(b0 + 0) * SEQ + t) * DI + tid];
            s_x[1][tid] = inputs[((size_t)(b0 + 1) * SEQ + t) * DI + tid];
        }
        __syncthreads();

        // ---- stage 1: gates. threads [0,128): r column j; [128,256): z column j.
        {
            const int j = tid & (DH - 1);
            const bool is_r = (tid < DH);
            const float* __restrict__ W = is_r ? r_w : z_w;
            const float bias = is_r ? r_b[j] : z_b[j];
            float aA0 = bias, aB0 = 0.f, aA1 = bias, aB1 = 0.f;
            #pragma unroll 4
            for (int i = 0; i < DI; i += 8)
                dot8x2(&s_x[0][i], &s_x[1][i], W + (size_t)i * DH, DH, j, aA0, aB0, aA1, aB1);
            #pragma unroll 4
            for (int i = 0; i < DH; i += 8)
                dot8x2(&s_h[0][i], &s_h[1][i], W + (size_t)(DI + i) * DH, DH, j, aA0, aB0, aA1, aB1);
            const float a0 = aA0 + aB0;
            const float a1 = aA1 + aB1;
            const float g0 = 1.f / (1.f + expf(-a0));
            const float g1 = 1.f / (1.f + expf(-a1));
            if (is_r) {
                s_rh[0][j] = g0 * s_h[0][j];
                s_rh[1][j] = g1 * s_h[1][j];
            } else {
                s_z[0][j] = g0;
                s_z[1][j] = g1;
            }
        }
        __syncthreads();

        // ---- stage 2: y0 = relu([x, r*h] @ h_w0 + b0), 144 outputs
        if (tid < DM) {
            const int k = tid;
            float aA0 = h_b0[k], aB0 = 0.f, aA1 = h_b0[k], aB1 = 0.f;
            // note: bias added twice-guard — only once: fix by starting aA1 from bias, aB* at 0
            aA1 = h_b0[k];
            #pragma unroll 4
            for (int i = 0; i < DI; i += 8)
                dot8x2(&s_x[0][i], &s_x[1][i], h_w0 + (size_t)i * DM, DM, k, aA0, aB0, aA1, aB1);
            #pragma unroll 4
            for (int i = 0; i < DH; i += 8)
                dot8x2(&s_rh[0][i], &s_rh[1][i], h_w0 + (size_t)(DI + i) * DM, DM, k, aA0, aB0, aA1, aB1);
            s_y0[0][k] = fmaxf(aA0 + aB0, 0.f);
            s_y0[1][k] = fmaxf(aA1 + aB1, 0.f);
        }
        __syncthreads();

        // ---- stage 3: y1 = relu(y0 @ h_w1 + b1), 144 outputs, dot length 144
        if (tid < DM) {
            const int k = tid;
            float aA0 = h_b1[k], aB0 = 0.f, aA1 = h_b1[k], aB1 = 0.f;
            #pragma unroll 4
            for (int i = 0; i < DM; i += 8)
                dot8x2(&s_y0[0][i], &s_y0[1][i], h_w1 + (size_t)i * DM, DM, k, aA0, aB0, aA1, aB1);
            s_y1[0][k] = fmaxf(aA0 + aB0, 0.f);
            s_y1[1][k] = fmaxf(aA1 + aB1, 0.f);
        }
        __syncthreads();

        // ---- stage 4: h_tilde = tanh(y1 @ h_w2 + b2); h = (1-z)*h + z*h_tilde
        if (tid < DH) {
            const int j = tid;
            float aA0 = h_b2[j], aB0 = 0.f, aA1 = h_b2[j], aB1 = 0.f;
            #pragma unroll 4
            for (int i = 0; i < DM; i += 8)
                dot8x2(&s_y1[0][i], &s_y1[1][i], h_w2 + (size_t)i * DH, DH, j, aA0, aB0, aA1, aB1);
            const float ht0 = tanhf(aA0 + aB0);
            const float ht1 = tanhf(aA1 + aB1);
            const float z0 = s_z[0][j], z1 = s_z[1][j];
            const float h0 = s_h[0][j], h1 = s_h[1][j];
            const float hn0 = (1.f - z0) * h0 + z0 * ht0;
            const float hn1 = (1.f - z1) * h1 + z1 * ht1;
            s_h[0][j] = hn0;
            s_h[1][j] = hn1;
            out[((size_t)(b0 + 0) * SEQ + t) * DH + j] = hn0;
            out[((size_t)(b0 + 1) * SEQ + t) * DH + j] = hn1;
        }
        __syncthreads();
    }

    if (tid < DH) {
        hid_out[(size_t)(b0 + 0) * DH + tid] = s_h[0][tid];
        hid_out[(size_t)(b0 + 1) * DH + tid] = s_h[1][tid];
    }
}

extern "C" void kernel_launch(void* const* d_in, const int* in_sizes, int n_in,
                              void* d_out, int out_size, void* d_ws, size_t ws_size,
                              hipStream_t stream) {
    const float* inputs = (const float*)d_in[0];
    const float* r_w  = (const float*)d_in[1];
    const float* r_b  = (const float*)d_in[2];
    const float* z_w  = (const float*)d_in[3];
    const float* z_b  = (const float*)d_in[4];
    const float* h_w0 = (const float*)d_in[5];
    const float* h_b0 = (const float*)d_in[6];
    const float* h_w1 = (const float*)d_in[7];
    const float* h_b1 = (const float*)d_in[8];
    const float* h_w2 = (const float*)d_in[9];
    const float* h_b2 = (const float*)d_in[10];

    float* out = (float*)d_out;
    float* hid = out + (size_t)BATCH * SEQ * DH;

    hipLaunchKernelGGL(hgru_kernel, dim3(BATCH / ROWS), dim3(256), 0, stream,
                       inputs, r_w, r_b, z_w, z_b,
                       h_w0, h_b0, h_w1, h_b1, h_w2, h_b2,
                       out, hid);
}

// Round 2
// 4286.879 us; speedup vs baseline: 3.8773x; 3.8773x over previous
//
#include <hip/hip_runtime.h>
#include <math.h>

typedef _Float16 h2 __attribute__((ext_vector_type(2)));

#define BATCH 256
#define SEQ   1024
#define DI    128
#define DH    128
#define DM    144
#define NT    512

__device__ __forceinline__ float fdot2(h2 a, h2 b, float c) {
#if __has_builtin(__builtin_amdgcn_fdot2)
    return __builtin_amdgcn_fdot2(a, b, c, false);
#else
    return c + (float)a.x * (float)b.x + (float)a.y * (float)b.y;
#endif
}

__device__ __forceinline__ h2 packf(float a, float b) {
    h2 r; r.x = (_Float16)a; r.y = (_Float16)b; return r;
}

__global__ __launch_bounds__(NT, 2) void hgru_kernel(
    const float* __restrict__ inputs,
    const float* __restrict__ r_w, const float* __restrict__ r_b,
    const float* __restrict__ z_w, const float* __restrict__ z_b,
    const float* __restrict__ h_w0, const float* __restrict__ h_b0,
    const float* __restrict__ h_w1, const float* __restrict__ h_b1,
    const float* __restrict__ h_w2, const float* __restrict__ h_b2,
    float* __restrict__ out, float* __restrict__ hid_out)
{
    // activations only — weights live in registers
    __shared__ __align__(16) h2       sh_x[2][64];    // x_t packed f16 pairs
    __shared__ __align__(16) h2       sh_h2[2][64];   // h packed f16 pairs
    __shared__ __align__(16) h2       sh_rh[2][64];   // r*h packed
    __shared__ __align__(16) _Float16 sh_y0[2][DM];   // mlp act 1
    __shared__ __align__(16) _Float16 sh_y1[2][DM];   // mlp act 2
    __shared__ __align__(16) float    sh_hf[2][DH];   // h fp32 (exact state)
    __shared__ __align__(16) float    sh_z[2][DH];
    __shared__ __align__(16) float    sh_p[2][256];   // k-split partials

    const int tid = threadIdx.x;
    const int b0  = blockIdx.x * 2;

    // ================= persistent register weights =================
    h2 wg[64];    // gate column half: task (gc in [0,256), gkh)
    h2 wm[100];   // class-dependent MLP weights

    const int  gc   = tid & 255;
    const int  gkh  = tid >> 8;          // wave-uniform
    const bool g_is_r = gc < DH;
    const int  gcc  = g_is_r ? gc : gc - DH;
    {
        const float* __restrict__ W = g_is_r ? r_w : z_w;
        #pragma unroll
        for (int m = 0; m < 64; ++m) {
            const int kin = gkh * 128 + 2 * m;
            wg[m] = packf(W[(size_t)kin * DH + gcc], W[(size_t)(kin + 1) * DH + gcc]);
        }
    }
    // classA: stage2 task (k2 = tid>>1, kh = tid&1), wm[0:64]
    if (tid < 288) {
        const int k2 = tid >> 1, kh = tid & 1;
        #pragma unroll
        for (int m = 0; m < 64; ++m) {
            const int kin = kh * 128 + 2 * m;
            wm[m] = packf(h_w0[(size_t)kin * DM + k2], h_w0[(size_t)(kin + 1) * DM + k2]);
        }
    }
    // stage3 leftover cols 112..143 on threads 0..63 -> wm[64:100]
    if (tid < 64) {
        const int k3 = 112 + (tid >> 1), kh = tid & 1;
        #pragma unroll
        for (int m = 0; m < 36; ++m) {
            const int kin = kh * 72 + 2 * m;
            wm[64 + m] = packf(h_w1[(size_t)kin * DM + k3], h_w1[(size_t)(kin + 1) * DM + k3]);
        }
    } else if (tid < 96) {
        // stage4 leftover cols 112..127 on threads 64..95 -> wm[64:100]
        const int j = 112 + ((tid - 64) >> 1), kh = (tid - 64) & 1;
        #pragma unroll
        for (int m = 0; m < 36; ++m) {
            const int kin = kh * 72 + 2 * m;
            wm[64 + m] = packf(h_w2[(size_t)kin * DH + j], h_w2[(size_t)(kin + 1) * DH + j]);
        }
    }
    // classB: stage3 col kb in wm[0:36], stage4 col kb in wm[36:72]
    if (tid >= 288) {
        const int t3 = tid - 288;
        const int kb = t3 >> 1, kh = t3 & 1;
        #pragma unroll
        for (int m = 0; m < 36; ++m) {
            const int kin = kh * 72 + 2 * m;
            wm[m]      = packf(h_w1[(size_t)kin * DM + kb], h_w1[(size_t)(kin + 1) * DM + kb]);
            wm[36 + m] = packf(h_w2[(size_t)kin * DH + kb], h_w2[(size_t)(kin + 1) * DH + kb]);
        }
    }

    // biases for finalizing threads
    float bias1 = 0.f, bias2 = 0.f, bias3 = 0.f, bias4 = 0.f;
    if (tid < 256) bias1 = g_is_r ? r_b[gcc] : z_b[gcc];
    if (tid < 288 && !(tid & 1)) bias2 = h_b0[tid >> 1];
    if (tid >= 288 && !((tid - 288) & 1)) {
        bias3 = h_b1[(tid - 288) >> 1];
        bias4 = h_b2[(tid - 288) >> 1];
    }
    if (tid < 64 && !(tid & 1))                 bias3 = h_b1[112 + (tid >> 1)];
    if (tid >= 64 && tid < 96 && !((tid - 64) & 1)) bias4 = h_b2[112 + ((tid - 64) >> 1)];

    // init h = 0; stage x_0 to LDS; prefetch x_1 into registers
    if (tid < 256) sh_hf[tid >> 7][tid & 127] = 0.f;
    float2 xpf = {0.f, 0.f};
    int xrow = 0, xmi = 0;
    const bool is_xldr = (tid >= 128 && tid < 256);
    if (is_xldr) {
        const int m = tid - 128; xrow = m >> 6; xmi = m & 63;
        float2 v = *((const float2*)(inputs + ((size_t)(b0 + xrow) * SEQ + 0) * DI) + xmi);
        sh_x[xrow][xmi] = packf(v.x, v.y);
        xpf = *((const float2*)(inputs + ((size_t)(b0 + xrow) * SEQ + 1) * DI) + xmi);
    }
    __syncthreads();

    for (int t = 0; t < SEQ; ++t) {
        // phase 0: repack h -> f16 pairs
        if (tid < 128) {
            const int row = tid >> 6, mi = tid & 63;
            sh_h2[row][mi] = packf(sh_hf[row][2 * mi], sh_hf[row][2 * mi + 1]);
        }
        __syncthreads(); // A

        // ---- stage 1: gates (all 512 threads) ----
        float s1a0, s1a1;
        {
            const h2* __restrict__ i0 = gkh ? sh_h2[0] : sh_x[0];
            const h2* __restrict__ i1 = gkh ? sh_h2[1] : sh_x[1];
            float a0 = 0.f, c0 = 0.f, a1 = 0.f, c1 = 0.f;
            #pragma unroll
            for (int m = 0; m < 64; m += 2) {
                a0 = fdot2(wg[m],     i0[m],     a0);
                c0 = fdot2(wg[m + 1], i0[m + 1], c0);
                a1 = fdot2(wg[m],     i1[m],     a1);
                c1 = fdot2(wg[m + 1], i1[m + 1], c1);
            }
            s1a0 = a0 + c0; s1a1 = a1 + c1;
        }
        if (gkh) { sh_p[0][gc] = s1a0; sh_p[1][gc] = s1a1; }
        __syncthreads(); // B
        if (!gkh) {
            const float a0 = s1a0 + sh_p[0][gc] + bias1;
            const float a1 = s1a1 + sh_p[1][gc] + bias1;
            const float g0 = 1.f / (1.f + __expf(-a0));
            const float g1 = 1.f / (1.f + __expf(-a1));
            if (g_is_r) {
                _Float16* rhp = (_Float16*)sh_rh;
                rhp[gcc]       = (_Float16)(g0 * sh_hf[0][gcc]);
                rhp[128 + gcc] = (_Float16)(g1 * sh_hf[1][gcc]);
            } else {
                sh_z[0][gcc] = g0;
                sh_z[1][gcc] = g1;
            }
        }
        __syncthreads(); // C

        // ---- stage 2: y0 = relu([x, r*h] @ h_w0 + b0) ----
        float s2a0 = 0.f, s2a1 = 0.f;
        if (tid < 288) {
            const int kh = tid & 1;
            const h2* __restrict__ i0 = kh ? sh_rh[0] : sh_x[0];
            const h2* __restrict__ i1 = kh ? sh_rh[1] : sh_x[1];
            float a0 = 0.f, c0 = 0.f, a1 = 0.f, c1 = 0.f;
            #pragma unroll
            for (int m = 0; m < 64; m += 2) {
                a0 = fdot2(wm[m],     i0[m],     a0);
                c0 = fdot2(wm[m + 1], i0[m + 1], c0);
                a1 = fdot2(wm[m],     i1[m],     a1);
                c1 = fdot2(wm[m + 1], i1[m + 1], c1);
            }
            s2a0 = a0 + c0; s2a1 = a1 + c1;
            if (kh) { sh_p[0][tid >> 1] = s2a0; sh_p[1][tid >> 1] = s2a1; }
        }
        __syncthreads(); // D
        if (tid < 288 && !(tid & 1)) {
            const int k2 = tid >> 1;
            const float y0 = fmaxf(s2a0 + sh_p[0][k2] + bias2, 0.f);
            const float y1 = fmaxf(s2a1 + sh_p[1][k2] + bias2, 0.f);
            ((_Float16*)sh_y0)[k2]      = (_Float16)y0;
            ((_Float16*)sh_y0)[DM + k2] = (_Float16)y1;
        }
        if (is_xldr) { // publish x_{t+1}; prefetch x_{t+2}
            sh_x[xrow][xmi] = packf(xpf.x, xpf.y);
            const int tn = (t + 2 < SEQ) ? t + 2 : SEQ - 1;
            xpf = *((const float2*)(inputs + ((size_t)(b0 + xrow) * SEQ + tn) * DI) + xmi);
        }
        __syncthreads(); // E

        // ---- stage 3: y1 = relu(y0 @ h_w1 + b1) ----
        float s3a0 = 0.f, s3a1 = 0.f;
        bool s3_fin = false; int s3k = 0;
        if (tid >= 288) {
            const int t3 = tid - 288, kh = t3 & 1;
            s3k = t3 >> 1; s3_fin = !kh;
            const h2* __restrict__ i0 = (const h2*)&sh_y0[0][0] + kh * 36;
            const h2* __restrict__ i1 = (const h2*)&sh_y0[1][0] + kh * 36;
            float a0 = 0.f, c0 = 0.f, a1 = 0.f, c1 = 0.f;
            #pragma unroll
            for (int m = 0; m < 36; m += 2) {
                a0 = fdot2(wm[m],     i0[m],     a0);
                c0 = fdot2(wm[m + 1], i0[m + 1], c0);
                a1 = fdot2(wm[m],     i1[m],     a1);
                c1 = fdot2(wm[m + 1], i1[m + 1], c1);
            }
            s3a0 = a0 + c0; s3a1 = a1 + c1;
            if (kh) { sh_p[0][s3k] = s3a0; sh_p[1][s3k] = s3a1; }
        } else if (tid < 64) {
            const int kh = tid & 1;
            s3k = 112 + (tid >> 1); s3_fin = !kh;
            const h2* __restrict__ i0 = (const h2*)&sh_y0[0][0] + kh * 36;
            const h2* __restrict__ i1 = (const h2*)&sh_y0[1][0] + kh * 36;
            float a0 = 0.f, c0 = 0.f, a1 = 0.f, c1 = 0.f;
            #pragma unroll
            for (int m = 0; m < 36; m += 2) {
                a0 = fdot2(wm[64 + m],     i0[m],     a0);
                c0 = fdot2(wm[64 + m + 1], i0[m + 1], c0);
                a1 = fdot2(wm[64 + m],     i1[m],     a1);
                c1 = fdot2(wm[64 + m + 1], i1[m + 1], c1);
            }
            s3a0 = a0 + c0; s3a1 = a1 + c1;
            if (kh) { sh_p[0][s3k] = s3a0; sh_p[1][s3k] = s3a1; }
        }
        __syncthreads(); // F
        if (s3_fin) {
            const float y0 = fmaxf(s3a0 + sh_p[0][s3k] + bias3, 0.f);
            const float y1 = fmaxf(s3a1 + sh_p[1][s3k] + bias3, 0.f);
            ((_Float16*)sh_y1)[s3k]      = (_Float16)y0;
            ((_Float16*)sh_y1)[DM + s3k] = (_Float16)y1;
        }
        __syncthreads(); // G

        // ---- stage 4: h~ = tanh(y1 @ h_w2 + b2); h = (1-z)h + z h~ ----
        float s4a0 = 0.f, s4a1 = 0.f;
        bool s4_fin = false; int s4j = 0;
        if (tid >= 288) {
            const int t4 = tid - 288, kh = t4 & 1;
            s4j = t4 >> 1; s4_fin = !kh;
            const h2* __restrict__ i0 = (const h2*)&sh_y1[0][0] + kh * 36;
            const h2* __restrict__ i1 = (const h2*)&sh_y1[1][0] + kh * 36;
            float a0 = 0.f, c0 = 0.f, a1 = 0.f, c1 = 0.f;
            #pragma unroll
            for (int m = 0; m < 36; m += 2) {
                a0 = fdot2(wm[36 + m],     i0[m],     a0);
                c0 = fdot2(wm[36 + m + 1], i0[m + 1], c0);
                a1 = fdot2(wm[36 + m],     i1[m],     a1);
                c1 = fdot2(wm[36 + m + 1], i1[m + 1], c1);
            }
            s4a0 = a0 + c0; s4a1 = a1 + c1;
            if (kh) { sh_p[0][s4j] = s4a0; sh_p[1][s4j] = s4a1; }
        } else if (tid >= 64 && tid < 96) {
            const int kh = (tid - 64) & 1;
            s4j = 112 + ((tid - 64) >> 1); s4_fin = !kh;
            const h2* __restrict__ i0 = (const h2*)&sh_y1[0][0] + kh * 36;
            const h2* __restrict__ i1 = (const h2*)&sh_y1[1][0] + kh * 36;
            float a0 = 0.f, c0 = 0.f, a1 = 0.f, c1 = 0.f;
            #pragma unroll
            for (int m = 0; m < 36; m += 2) {
                a0 = fdot2(wm[64 + m],     i0[m],     a0);
                c0 = fdot2(wm[64 + m + 1], i0[m + 1], c0);
                a1 = fdot2(wm[64 + m],     i1[m],     a1);
                c1 = fdot2(wm[64 + m + 1], i1[m + 1], c1);
            }
            s4a0 = a0 + c0; s4a1 = a1 + c1;
            if (kh) { sh_p[0][s4j] = s4a0; sh_p[1][s4j] = s4a1; }
        }
        __syncthreads(); // H
        if (s4_fin) {
            const float a0 = s4a0 + sh_p[0][s4j] + bias4;
            const float a1 = s4a1 + sh_p[1][s4j] + bias4;
            const float e0 = __expf(2.f * a0), e1 = __expf(2.f * a1);
            const float ht0 = 1.f - 2.f / (e0 + 1.f);
            const float ht1 = 1.f - 2.f / (e1 + 1.f);
            const float z0 = sh_z[0][s4j], z1 = sh_z[1][s4j];
            const float h0 = sh_hf[0][s4j], h1 = sh_hf[1][s4j];
            const float hn0 = (1.f - z0) * h0 + z0 * ht0;
            const float hn1 = (1.f - z1) * h1 + z1 * ht1;
            sh_hf[0][s4j] = hn0; sh_hf[1][s4j] = hn1;
            out[((size_t)(b0 + 0) * SEQ + t) * DH + s4j] = hn0;
            out[((size_t)(b0 + 1) * SEQ + t) * DH + s4j] = hn1;
        }
        __syncthreads(); // I
    }

    if (tid < 256) {
        const int row = tid >> 7, j = tid & 127;
        hid_out[(size_t)(b0 + row) * DH + j] = sh_hf[row][j];
    }
}

extern "C" void kernel_launch(void* const* d_in, const int* in_sizes, int n_in,
                              void* d_out, int out_size, void* d_ws, size_t ws_size,
                              hipStream_t stream) {
    const float* inputs = (const float*)d_in[0];
    const float* r_w  = (const float*)d_in[1];
    const float* r_b  = (const float*)d_in[2];
    const float* z_w  = (const float*)d_in[3];
    const float* z_b  = (const float*)d_in[4];
    const float* h_w0 = (const float*)d_in[5];
    const float* h_b0 = (const float*)d_in[6];
    const float* h_w1 = (const float*)d_in[7];
    const float* h_b1 = (const float*)d_in[8];
    const float* h_w2 = (const float*)d_in[9];
    const float* h_b2 = (const float*)d_in[10];

    float* out = (float*)d_out;
    float* hid = out + (size_t)BATCH * SEQ * DH;

    hipLaunchKernelGGL(hgru_kernel, dim3(BATCH / 2), dim3(NT), 0, stream,
                       inputs, r_w, r_b, z_w, z_b,
                       h_w0, h_b0, h_w1, h_b1, h_w2, h_b2,
                       out, hid);
}

// Round 3
// 3407.491 us; speedup vs baseline: 4.8780x; 1.2581x over previous
//
#include <hip/hip_runtime.h>
#include <math.h>

typedef _Float16 f16;
typedef _Float16 f16x8 __attribute__((ext_vector_type(8)));
typedef _Float16 f16x4 __attribute__((ext_vector_type(4)));
typedef float    f32x4 __attribute__((ext_vector_type(4)));

#define BATCH 256
#define SEQ   1024
#define DI    128
#define DH    128
#define DM    144
#define NT    512
#define MR    16

// XOR-swizzle: permutes 16B slots within a 128B-aligned row region (T2/G4).
#define SWZB(b, m) ((b) ^ (((m) & 7) << 4))
#define MFMA16(a, b, c) __builtin_amdgcn_mfma_f32_16x16x32_f16((a), (b), (c), 0, 0, 0)
// A-fragment read: row = ln (lane&15), 8 consecutive k starting at k0 (=16B, aligned)
#define AFRAG(base, ldb, k0) (*(const f16x8*)((const char*)(base) + SWZB((ln) * (ldb) + 2 * (k0), ln)))

__global__ __launch_bounds__(NT, 1) void hgru_kernel(
    const float* __restrict__ inputs,
    const float* __restrict__ r_w, const float* __restrict__ r_b,
    const float* __restrict__ z_w, const float* __restrict__ z_b,
    const float* __restrict__ h_w0, const float* __restrict__ h_b0,
    const float* __restrict__ h_w1, const float* __restrict__ h_b1,
    const float* __restrict__ h_w2, const float* __restrict__ h_b2,
    float* __restrict__ out, float* __restrict__ hid_out)
{
    __shared__ __align__(16) f16  sx[2][MR][128];  // x_t panels (double buffer), swizzled
    __shared__ __align__(16) f16  sh16[MR][128];   // h as f16 A-panel, swizzled
    __shared__ __align__(16) f16  srh[MR][128];    // r*h A-panel, swizzled
    __shared__ __align__(16) f16  sy0[MR][192];    // mlp act1, K padded 144->192(zeros), swizzled
    __shared__ __align__(16) f16  sy1[MR][192];    // mlp act2
    __shared__ __align__(16) float sz[MR][DH];     // z gate f32
    __shared__ __align__(16) float shf[MR][DH];    // master h state f32

    const int tid  = threadIdx.x;
    const int w    = tid >> 6;     // wave 0..7
    const int lane = tid & 63;
    const int ln   = lane & 15;    // A-row / B-col / C-col
    const int kg   = lane >> 4;    // k-group
    const int mr0  = kg * 4;       // C-row base
    const int b0   = blockIdx.x * MR;

    // ---- zero-init LDS (pads of sy0/sy1 must stay 0 forever) ----
    for (int i = tid; i < MR * 192; i += NT) { (&sy0[0][0])[i] = (f16)0.f; (&sy1[0][0])[i] = (f16)0.f; }
    for (int i = tid; i < MR * DH;  i += NT) { (&shf[0][0])[i] = 0.f; (&sh16[0][0])[i] = (f16)0.f; }

    // ================= register-resident weight B-fragments =================
    // B-frag element j of k-tile kt: W[kt*32 + kg*8 + j][n],  n = tile*16 + ln
    const bool is_r = (w < 4);
    const int  cb   = (w & 3) * 32;              // gate column base (2 tiles/wave)
    const float* __restrict__ Wg = is_r ? r_w : z_w;

    f16x8 wg[2][8];                               // gates: 2 N-tiles x 8 K-tiles
    #pragma unroll
    for (int n2 = 0; n2 < 2; ++n2)
        #pragma unroll
        for (int kt = 0; kt < 8; ++kt) {
            f16x8 f;
            #pragma unroll
            for (int j = 0; j < 8; ++j)
                f[j] = (f16)Wg[(size_t)(kt * 32 + kg * 8 + j) * DH + cb + n2 * 16 + ln];
            wg[n2][kt] = f;
        }

    f16x8 w0f[2][8], w1f[2][5], w2f[5];           // [1] slots only used by wave 7 (tile 8)
    #pragma unroll
    for (int kt = 0; kt < 8; ++kt) {
        f16x8 f, f2;
        #pragma unroll
        for (int j = 0; j < 8; ++j) {
            const int k = kt * 32 + kg * 8 + j;
            f[j]  = (f16)h_w0[(size_t)k * DM + w * 16 + ln];
            f2[j] = (f16)h_w0[(size_t)k * DM + 128 + ln];
        }
        w0f[0][kt] = f; w0f[1][kt] = f2;
    }
    #pragma unroll
    for (int kt = 0; kt < 5; ++kt) {              // K 144 padded to 160 with zeros
        f16x8 f, f2, f3;
        #pragma unroll
        for (int j = 0; j < 8; ++j) {
            const int k = kt * 32 + kg * 8 + j;
            f[j]  = (k < DM) ? (f16)h_w1[(size_t)k * DM + w * 16 + ln] : (f16)0.f;
            f2[j] = (k < DM) ? (f16)h_w1[(size_t)k * DM + 128 + ln]    : (f16)0.f;
            f3[j] = (k < DM) ? (f16)h_w2[(size_t)k * DH + w * 16 + ln] : (f16)0.f;
        }
        w1f[0][kt] = f; w1f[1][kt] = f2; w2f[kt] = f3;
    }

    const float bs10 = is_r ? r_b[cb + ln]      : z_b[cb + ln];
    const float bs11 = is_r ? r_b[cb + 16 + ln] : z_b[cb + 16 + ln];
    const float b20  = h_b0[w * 16 + ln];
    const float b21  = h_b0[128 + ln];
    const float b30  = h_b1[w * 16 + ln];
    const float b31  = h_b1[128 + ln];
    const float b40  = h_b2[w * 16 + ln];

    // ---- x staging: thread -> (row, float4) ----
    const int xr = tid >> 5;
    const int xc = tid & 31;
    float4 xp = ((const float4*)(inputs + ((size_t)(b0 + xr) * SEQ + 0) * DI))[xc];
    {
        f16x4 v; v[0] = (f16)xp.x; v[1] = (f16)xp.y; v[2] = (f16)xp.z; v[3] = (f16)xp.w;
        *(f16x4*)((char*)&sx[0][0][0] + SWZB(xr * 256 + xc * 8, xr)) = v;
    }
    __syncthreads();

    const f32x4 z4 = {0.f, 0.f, 0.f, 0.f};

    for (int t = 0; t < SEQ; ++t) {
        const char* xb = (const char*)&sx[t & 1][0][0];

        // prefetch x_{t+1} (global latency hides under the whole step)
        {
            const int tn = (t + 1 < SEQ) ? t + 1 : SEQ - 1;
            xp = ((const float4*)(inputs + ((size_t)(b0 + xr) * SEQ + tn) * DI))[xc];
        }

        // ============ stage 1: gates  C[16,256] = [x|h] @ [r_w|z_w] ============
        const f16x8 xa0 = AFRAG(xb, 256, kg * 8);
        const f16x8 xa1 = AFRAG(xb, 256, 32 + kg * 8);
        const f16x8 xa2 = AFRAG(xb, 256, 64 + kg * 8);
        const f16x8 xa3 = AFRAG(xb, 256, 96 + kg * 8);

        f32x4 aA0 = z4, aB0 = z4, aA1 = z4, aB1 = z4;
        aA0 = MFMA16(xa0, wg[0][0], aA0);  aA1 = MFMA16(xa0, wg[1][0], aA1);
        aB0 = MFMA16(xa1, wg[0][1], aB0);  aB1 = MFMA16(xa1, wg[1][1], aB1);
        aA0 = MFMA16(xa2, wg[0][2], aA0);  aA1 = MFMA16(xa2, wg[1][2], aA1);
        aB0 = MFMA16(xa3, wg[0][3], aB0);  aB1 = MFMA16(xa3, wg[1][3], aB1);
        {
            const f16x8 ha0 = AFRAG(sh16, 256, kg * 8);
            const f16x8 ha1 = AFRAG(sh16, 256, 32 + kg * 8);
            const f16x8 ha2 = AFRAG(sh16, 256, 64 + kg * 8);
            const f16x8 ha3 = AFRAG(sh16, 256, 96 + kg * 8);
            aA0 = MFMA16(ha0, wg[0][4], aA0);  aA1 = MFMA16(ha0, wg[1][4], aA1);
            aB0 = MFMA16(ha1, wg[0][5], aB0);  aB1 = MFMA16(ha1, wg[1][5], aB1);
            aA0 = MFMA16(ha2, wg[0][6], aA0);  aA1 = MFMA16(ha2, wg[1][6], aA1);
            aB0 = MFMA16(ha3, wg[0][7], aB0);  aB1 = MFMA16(ha3, wg[1][7], aB1);
        }
        const f32x4 g0 = aA0 + aB0;
        const f32x4 g1 = aA1 + aB1;

        #pragma unroll
        for (int n2 = 0; n2 < 2; ++n2) {
            const f32x4 g  = n2 ? g1 : g0;
            const float bs = n2 ? bs11 : bs10;
            const int   n  = cb + n2 * 16 + ln;
            #pragma unroll
            for (int j = 0; j < 4; ++j) {
                const int m = mr0 + j;
                const float s = 1.f / (1.f + __expf(-(g[j] + bs)));
                if (is_r) {
                    *(f16*)((char*)&srh[0][0] + SWZB(m * 256 + 2 * n, m)) = (f16)(s * shf[m][n]);
                } else {
                    sz[m][n] = s;
                }
            }
        }
        __syncthreads(); // A: rh, z published

        // ============ stage 2: y0 = relu([x|r*h] @ h_w0 + b0)  N=144 ============
        f32x4 pA0 = z4, pB0 = z4, pA1 = z4, pB1 = z4;
        pA0 = MFMA16(xa0, w0f[0][0], pA0);
        pB0 = MFMA16(xa1, w0f[0][1], pB0);
        pA0 = MFMA16(xa2, w0f[0][2], pA0);
        pB0 = MFMA16(xa3, w0f[0][3], pB0);
        if (w == 7) {
            pA1 = MFMA16(xa0, w0f[1][0], pA1);
            pB1 = MFMA16(xa1, w0f[1][1], pB1);
            pA1 = MFMA16(xa2, w0f[1][2], pA1);
            pB1 = MFMA16(xa3, w0f[1][3], pB1);
        }
        {
            const f16x8 ra0 = AFRAG(srh, 256, kg * 8);
            const f16x8 ra1 = AFRAG(srh, 256, 32 + kg * 8);
            const f16x8 ra2 = AFRAG(srh, 256, 64 + kg * 8);
            const f16x8 ra3 = AFRAG(srh, 256, 96 + kg * 8);
            pA0 = MFMA16(ra0, w0f[0][4], pA0);
            pB0 = MFMA16(ra1, w0f[0][5], pB0);
            pA0 = MFMA16(ra2, w0f[0][6], pA0);
            pB0 = MFMA16(ra3, w0f[0][7], pB0);
            if (w == 7) {
                pA1 = MFMA16(ra0, w0f[1][4], pA1);
                pB1 = MFMA16(ra1, w0f[1][5], pB1);
                pA1 = MFMA16(ra2, w0f[1][6], pA1);
                pB1 = MFMA16(ra3, w0f[1][7], pB1);
            }
        }
        {
            const f32x4 y0v = pA0 + pB0;
            #pragma unroll
            for (int j = 0; j < 4; ++j) {
                const int m = mr0 + j;
                *(f16*)((char*)&sy0[0][0] + SWZB(m * 384 + 2 * (w * 16 + ln), m)) =
                    (f16)fmaxf(y0v[j] + b20, 0.f);
            }
            if (w == 7) {
                const f32x4 y0w = pA1 + pB1;
                #pragma unroll
                for (int j = 0; j < 4; ++j) {
                    const int m = mr0 + j;
                    *(f16*)((char*)&sy0[0][0] + SWZB(m * 384 + 2 * (128 + ln), m)) =
                        (f16)fmaxf(y0w[j] + b21, 0.f);
                }
            }
        }
        __syncthreads(); // B: y0 published

        // ============ stage 3: y1 = relu(y0 @ h_w1 + b1)  K=144(+pad), N=144 ============
        f32x4 qA = z4, qB = z4, qA1 = z4, qB1 = z4;
        #pragma unroll
        for (int kt = 0; kt < 5; ++kt) {
            const f16x8 a = AFRAG(sy0, 384, kt * 32 + kg * 8);
            if (kt & 1) { qB = MFMA16(a, w1f[0][kt], qB); if (w == 7) qB1 = MFMA16(a, w1f[1][kt], qB1); }
            else        { qA = MFMA16(a, w1f[0][kt], qA); if (w == 7) qA1 = MFMA16(a, w1f[1][kt], qA1); }
        }
        {
            const f32x4 y1v = qA + qB;
            #pragma unroll
            for (int j = 0; j < 4; ++j) {
                const int m = mr0 + j;
                *(f16*)((char*)&sy1[0][0] + SWZB(m * 384 + 2 * (w * 16 + ln), m)) =
                    (f16)fmaxf(y1v[j] + b30, 0.f);
            }
            if (w == 7) {
                const f32x4 y1w = qA1 + qB1;
                #pragma unroll
                for (int j = 0; j < 4; ++j) {
                    const int m = mr0 + j;
                    *(f16*)((char*)&sy1[0][0] + SWZB(m * 384 + 2 * (128 + ln), m)) =
                        (f16)fmaxf(y1w[j] + b31, 0.f);
                }
            }
        }
        __syncthreads(); // C: y1 published

        // ============ stage 4: h~ = tanh(y1 @ h_w2 + b2); h update ============
        f32x4 rA = z4, rB = z4;
        #pragma unroll
        for (int kt = 0; kt < 5; ++kt) {
            const f16x8 a = AFRAG(sy1, 384, kt * 32 + kg * 8);
            if (kt & 1) rB = MFMA16(a, w2f[kt], rB);
            else        rA = MFMA16(a, w2f[kt], rA);
        }
        const f32x4 hv = rA + rB;

        // publish x_{t+1} into the other buffer (its readers finished at step t-1)
        {
            f16x4 v; v[0] = (f16)xp.x; v[1] = (f16)xp.y; v[2] = (f16)xp.z; v[3] = (f16)xp.w;
            *(f16x4*)((char*)&sx[(t + 1) & 1][0][0] + SWZB(xr * 256 + xc * 8, xr)) = v;
        }

        {
            const int n4 = w * 16 + ln;
            #pragma unroll
            for (int j = 0; j < 4; ++j) {
                const int m  = mr0 + j;
                const float a  = hv[j] + b40;
                const float e  = __expf(2.f * a);
                const float ht = 1.f - 2.f / (e + 1.f);
                const float zz = sz[m][n4];
                const float hn = (1.f - zz) * shf[m][n4] + zz * ht;
                shf[m][n4] = hn;
                *(f16*)((char*)&sh16[0][0] + SWZB(m * 256 + 2 * n4, m)) = (f16)hn;
                out[((size_t)(b0 + m) * SEQ + t) * DH + n4] = hn;
            }
        }
        __syncthreads(); // D: h, x_{t+1} published
    }

    for (int i = tid; i < MR * DH; i += NT)
        hid_out[(size_t)(b0 + (i >> 7)) * DH + (i & 127)] = (&shf[0][0])[i];
}

extern "C" void kernel_launch(void* const* d_in, const int* in_sizes, int n_in,
                              void* d_out, int out_size, void* d_ws, size_t ws_size,
                              hipStream_t stream) {
    const float* inputs = (const float*)d_in[0];
    const float* r_w  = (const float*)d_in[1];
    const float* r_b  = (const float*)d_in[2];
    const float* z_w  = (const float*)d_in[3];
    const float* z_b  = (const float*)d_in[4];
    const float* h_w0 = (const float*)d_in[5];
    const float* h_b0 = (const float*)d_in[6];
    const float* h_w1 = (const float*)d_in[7];
    const float* h_b1 = (const float*)d_in[8];
    const float* h_w2 = (const float*)d_in[9];
    const float* h_b2 = (const float*)d_in[10];

    float* out = (float*)d_out;
    float* hid = out + (size_t)BATCH * SEQ * DH;

    hipLaunchKernelGGL(hgru_kernel, dim3(BATCH / MR), dim3(NT), 0, stream,
                       inputs, r_w, r_b, z_w, z_b,
                       h_w0, h_b0, h_w1, h_b1, h_w2, h_b2,
                       out, hid);
}